// Round 6
// baseline (1305.805 us; speedup 1.0000x reference)
//
#include <hip/hip_runtime.h>
#include <hip/hip_cooperative_groups.h>

namespace cg = cooperative_groups;

#define CIN 32
#define COUT 64
#define OD0 100
#define OD1 100
#define OD2 8
#define IZ 200
#define IY 200
#define IX 16
#define NTAP 27
#define NCELLS (2 * IZ * IY * IX)   // 1,280,000  (divisible by 1024)
#define TOY 4
#define TOX 8
#define NROW 27                      // 3 planes x 9 y-rows
#define NCELL_R (NROW * 16)          // 432 region cells
#define NBIN 12                      // (plane, y-parity, x-parity)
#define CAPB 64                      // per-bin worklist capacity (avg ~12)

#define ALOAD(p)     __hip_atomic_load((p), __ATOMIC_RELAXED, __HIP_MEMORY_SCOPE_AGENT)
#define ASTORE(p, v) __hip_atomic_store((p), (v), __ATOMIC_RELAXED, __HIP_MEMORY_SCOPE_AGENT)

// ================= fused cooperative preamble =================
// zero + W transpose + 4-level radix rank-select + CSR count/scan/scatter,
// one launch, 12 grid syncs. Cross-XCD: atomics for RMW, __hip_atomic for
// cross-block scalar/prefix traffic, __threadfence before every sync.

__global__ void __launch_bounds__(256)
preamble_kernel(const float* __restrict__ mask, const int* __restrict__ coors,
                const float* __restrict__ W, int n, int rank,
                int* __restrict__ hist, int* __restrict__ state,
                int* __restrict__ S, int* __restrict__ part,
                int* __restrict__ entries, float* __restrict__ Wt) {
    cg::grid_group g = cg::this_grid();
    __shared__ int h[256];
    __shared__ int sums[256];
    int tid = threadIdx.x, bid = blockIdx.x;
    int gtid = bid * 256 + tid;
    int gsz = gridDim.x * 256;

    // ---- phase A: zero S + hist, transpose W ----
    for (int i = gtid; i < NCELLS; i += gsz) S[i] = 0;
    for (int i = gtid; i < 4 * 256; i += gsz) hist[i] = 0;
    for (int i = gtid; i < NTAP * CIN * COUT; i += gsz) {
        int cout = i % COUT;
        int rest = i / COUT;
        int cin = rest % CIN;
        int tap = rest / CIN;
        Wt[((size_t)tap * COUT + cout) * CIN + cin] = W[i];
    }
    __threadfence();
    g.sync();

    // ---- 4-level 8-bit radix selection (level 0 fused with CSR count) ----
    for (int lvl = 0; lvl < 4; lvl++) {
        h[tid] = 0;
        __syncthreads();
        int sh = 24 - 8 * lvl;
        unsigned pfx = lvl ? (unsigned)ALOAD(&state[0]) : 0u;
        if (lvl == 0) {
            for (int i = gtid; i < n; i += gsz) {
                unsigned bits = __float_as_uint(mask[i]);   // mask in [0,1): uint order == float order
                atomicAdd(&h[bits >> 24], 1);
                const int4 c = ((const int4*)coors)[i];
                atomicAdd(&S[((c.x * IZ + c.y) * IY + c.z) * IX + c.w], 1);
            }
        } else {
            for (int i = gtid; i < n; i += gsz) {
                unsigned bits = __float_as_uint(mask[i]);
                if ((bits >> (sh + 8)) == pfx) atomicAdd(&h[(bits >> sh) & 0xFF], 1);
            }
        }
        __syncthreads();
        if (h[tid]) atomicAdd(&hist[lvl * 256 + tid], h[tid]);
        __threadfence();
        g.sync();

        if (bid == 0) {
            sums[tid] = ALOAD(&hist[lvl * 256 + tid]);
            __syncthreads();
            if (tid == 0) {
                int rk = lvl ? state[1] : rank;     // own prior atomic store
                unsigned p2 = lvl ? (unsigned)state[0] : 0u;
                int c = 0;
                for (int j = 0; j < 256; j++) {
                    int hv = sums[j];
                    if (rk < c + hv) {
                        ASTORE(&state[0], (int)((p2 << 8) | (unsigned)j));
                        ASTORE(&state[1], rk - c);
                        break;
                    }
                    c += hv;
                }
            }
            __syncthreads();
        }
        __threadfence();
        g.sync();
    }

    // ---- CSR scan: level 0 over 1024-int chunks ----
    int nChunks = NCELLS / 1024;                    // 1250
    for (int ch = bid; ch < nChunks; ch += gridDim.x) {
        int base = ch * 1024 + tid * 4;
        int vx = ALOAD(&S[base + 0]);               // atomic: S written by remote atomics
        int vy = ALOAD(&S[base + 1]);
        int vz = ALOAD(&S[base + 2]);
        int vw = ALOAD(&S[base + 3]);
        int s1 = vx + vy, s2 = s1 + vz, s3 = s2 + vw;
        sums[tid] = s3;
        __syncthreads();
        for (int off = 1; off < 256; off <<= 1) {
            int t2 = (tid >= off) ? sums[tid - off] : 0;
            __syncthreads();
            sums[tid] += t2;
            __syncthreads();
        }
        int excl = sums[tid] - s3;
        int4 o;
        o.x = excl; o.y = excl + vx; o.z = excl + s1; o.w = excl + s2;
        ((int4*)S)[ch * 256 + tid] = o;
        if (tid == 255) ASTORE(&part[ch], sums[255]);
        __syncthreads();
    }
    __threadfence();
    g.sync();

    // ---- scan level 1 (block 0) ----
    if (bid == 0) {
        int per = (nChunks + 255) / 256;            // 5
        int lo = tid * per, hi = lo + per;
        if (hi > nChunks) hi = nChunks;
        int s = 0;
        for (int j = lo; j < hi; j++) s += ALOAD(&part[j]);
        sums[tid] = s;
        __syncthreads();
        for (int off = 1; off < 256; off <<= 1) {
            int t2 = (tid >= off) ? sums[tid - off] : 0;
            __syncthreads();
            sums[tid] += t2;
            __syncthreads();
        }
        int run = sums[tid] - s;
        for (int j = lo; j < hi; j++) {
            int v = ALOAD(&part[j]);
            ASTORE(&part[j], run);
            run += v;
        }
    }
    __threadfence();
    g.sync();

    // ---- scan level 2 (same chunk assignment as level 0 -> local lines) ----
    for (int ch = bid; ch < nChunks; ch += gridDim.x) {
        int add = ALOAD(&part[ch]);
        if (add != 0) {
            int4 v = ((int4*)S)[ch * 256 + tid];
            v.x += add; v.y += add; v.z += add; v.w += add;
            ((int4*)S)[ch * 256 + tid] = v;
        }
    }
    __threadfence();
    g.sync();

    // ---- scatter points; S[c] becomes end-of-range ----
    float thr = __uint_as_float((unsigned)ALOAD(&state[0]));
    for (int i = gtid; i < n; i += gsz) {
        const int4 c = ((const int4*)coors)[i];
        int cell = ((c.x * IZ + c.y) * IY + c.z) * IX + c.w;
        int imp = (mask[i] >= thr) ? 1 : 0;
        int pos = atomicAdd(&S[cell], 1);
        entries[pos] = (i << 1) | imp;
    }
}

// ================= fallback preamble kernels (non-cooperative) =================

__global__ void hist0_fused_kernel(const float* __restrict__ mask, const int* __restrict__ coors,
                                   const float* __restrict__ W, int n,
                                   int* __restrict__ hist, int* __restrict__ S,
                                   float* __restrict__ Wt) {
    __shared__ int h[256];
    h[threadIdx.x] = 0;
    __syncthreads();
    for (int i = blockIdx.x * blockDim.x + threadIdx.x; i < n; i += gridDim.x * blockDim.x) {
        unsigned bits = __float_as_uint(mask[i]);
        atomicAdd(&h[bits >> 24], 1);
        const int4 c = ((const int4*)coors)[i];
        atomicAdd(&S[((c.x * IZ + c.y) * IY + c.z) * IX + c.w], 1);
    }
    for (int i = blockIdx.x * blockDim.x + threadIdx.x; i < NTAP * CIN * COUT;
         i += gridDim.x * blockDim.x) {
        int cout = i % COUT;
        int rest = i / COUT;
        int cin = rest % CIN;
        int tap = rest / CIN;
        Wt[((size_t)tap * COUT + cout) * CIN + cin] = W[i];
    }
    __syncthreads();
    int v = h[threadIdx.x];
    if (v) atomicAdd(&hist[threadIdx.x], v);
}

__global__ void hist8_kernel(const float* __restrict__ mask, int n, int level,
                             const int* __restrict__ state, int* __restrict__ hist) {
    __shared__ int h[256];
    h[threadIdx.x] = 0;
    __syncthreads();
    unsigned pfx = (unsigned)state[0];
    int sh = 24 - 8 * level;
    for (int i = blockIdx.x * blockDim.x + threadIdx.x; i < n; i += gridDim.x * blockDim.x) {
        unsigned bits = __float_as_uint(mask[i]);
        if ((bits >> (sh + 8)) == pfx)
            atomicAdd(&h[(bits >> sh) & 0xFF], 1);
    }
    __syncthreads();
    int v = h[threadIdx.x];
    if (v) atomicAdd(&hist[threadIdx.x], v);
}

__global__ void select8_kernel(const int* __restrict__ hist, int* __restrict__ state,
                               int level, int rankConst) {
    __shared__ int sc[256];
    sc[threadIdx.x] = hist[threadIdx.x];
    __syncthreads();
    if (threadIdx.x == 0) {
        int rank = level ? state[1] : rankConst;
        unsigned pfx = level ? (unsigned)state[0] : 0u;
        int c = 0;
        for (int j = 0; j < 256; j++) {
            int hv = sc[j];
            if (rank < c + hv) {
                state[0] = (int)((pfx << 8) | (unsigned)j);
                state[1] = rank - c;
                break;
            }
            c += hv;
        }
    }
}

__global__ void scan_l0_kernel(int* __restrict__ S, int* __restrict__ partials) {
    __shared__ int ts[256];
    int tid = threadIdx.x;
    int4 v = ((int4*)S)[blockIdx.x * 256 + tid];
    int s1 = v.x + v.y, s2 = s1 + v.z, s3 = s2 + v.w;
    ts[tid] = s3;
    __syncthreads();
    for (int off = 1; off < 256; off <<= 1) {
        int t = (tid >= off) ? ts[tid - off] : 0;
        __syncthreads();
        ts[tid] += t;
        __syncthreads();
    }
    int excl = ts[tid] - s3;
    int4 o;
    o.x = excl; o.y = excl + v.x; o.z = excl + s1; o.w = excl + s2;
    ((int4*)S)[blockIdx.x * 256 + tid] = o;
    if (tid == 255) partials[blockIdx.x] = ts[255];
}

__global__ void scan_l1_kernel(int* __restrict__ partials, int nP) {
    __shared__ int sums[256];
    int tid = threadIdx.x;
    int per = (nP + 255) / 256;
    int lo = tid * per, hi = lo + per;
    if (hi > nP) hi = nP;
    int s = 0;
    for (int j = lo; j < hi; j++) s += partials[j];
    sums[tid] = s;
    __syncthreads();
    for (int off = 1; off < 256; off <<= 1) {
        int t = (tid >= off) ? sums[tid - off] : 0;
        __syncthreads();
        sums[tid] += t;
        __syncthreads();
    }
    int run = sums[tid] - s;
    for (int j = lo; j < hi; j++) { int v = partials[j]; partials[j] = run; run += v; }
}

__global__ void scan_l2_kernel(int* __restrict__ S, const int* __restrict__ partials) {
    int add = partials[blockIdx.x];
    if (add == 0) return;
    int4 v = ((int4*)S)[blockIdx.x * 256 + threadIdx.x];
    v.x += add; v.y += add; v.z += add; v.w += add;
    ((int4*)S)[blockIdx.x * 256 + threadIdx.x] = v;
}

__global__ void scatter_points_kernel(const int* __restrict__ coors, const float* __restrict__ mask,
                                      const int* __restrict__ state, int n,
                                      int* __restrict__ S, int* __restrict__ entries) {
    int i = blockIdx.x * blockDim.x + threadIdx.x;
    if (i >= n) return;
    const int4 c = ((const int4*)coors)[i];
    int cell = ((c.x * IZ + c.y) * IY + c.z) * IX + c.w;
    float thr = __uint_as_float((unsigned)state[0]);
    int imp = (mask[i] >= thr) ? 1 : 0;
    int pos = atomicAdd(&S[cell], 1);
    entries[pos] = (i << 1) | imp;
}

// ================= main conv =================
// Block = 4x8 output tile at fixed (bb, oz). Input region = 3 planes x 9 rows x 16.
// Phase 0: region S -> LDS (459 ints, coalesced).
// Phase 1: threads own cells; push (pid|imp|pyL|px) into one of 12 bins keyed
//          (plane, y-parity, x-parity).
// Phase 2: waves take taps round-robin; weight column in regs; BRANCHLESS scan
//          of the matching bin (86% hit; misses go to dummy acc row 32) ->
//          feat loads pipeline deeply. One LDS atomicAdd per scan.
// Epilogue: one coalesced 256B store per cell, prune fused.

__global__ void __launch_bounds__(256)
conv_kernel(const float* __restrict__ feat, const float* __restrict__ Wt,
            const int* __restrict__ S, const int* __restrict__ entries,
            float* __restrict__ out) {
    __shared__ float accS[TOY * TOX + 1][COUT];   // +1 dummy row; 8448 B
    __shared__ int   sLds[NROW][17];              // 1836 B
    __shared__ unsigned work[NBIN][CAPB];         // 3072 B
    __shared__ int   cnt[NBIN];
    __shared__ int   keepS[TOY * TOX];
    __shared__ int   notDone;

    int tid = threadIdx.x;
    int w = tid >> 6;
    int lane = tid & 63;

    int tile = blockIdx.x;
    int oyT = (tile % (OD1 / TOY)) * TOY;
    int rest = tile / (OD1 / TOY);
    int oz = rest % OD0;
    int bb = rest / OD0;

    {   // zero accumulators (33 rows x 64 = 528 float4)
        float4 z = make_float4(0.f, 0.f, 0.f, 0.f);
        float4* a4 = (float4*)&accS[0][0];
        for (int i = tid; i < (TOY * TOX + 1) * (COUT / 4); i += 256) a4[i] = z;
        if (tid < TOY * TOX) keepS[tid] = 0;
    }

    // ---- phase 0: region S -> LDS ----
    for (int idx = tid; idx < NROW * 17; idx += 256) {
        int row = idx / 17, j = idx % 17;
        int plane = row / 9, pyL = row % 9;
        int pz = 2 * oz - 1 + plane;
        int py = 2 * oyT - 1 + pyL;
        int v = 0;
        if (pz >= 0 && py >= 0) {                 // upper bounds never exceeded
            int cellFlat = ((bb * IZ + pz) * IY + py) * IX + (j - 1);
            if (cellFlat >= 0) v = S[cellFlat];
        }
        sLds[row][j] = v;
    }

    int ci = tid;     // region cell, strided by 256
    int pi = -1;      // resume entry index within current cell (-1 = range start)

    for (;;) {
        if (tid < NBIN) cnt[tid] = 0;
        if (tid == 0) notDone = 0;
        __syncthreads();   // covers sLds/accS init on first pass

        // ---- phase 1: enumerate points into 12 bins ----
        while (ci < NCELL_R) {
            int row = ci >> 4, px = ci & 15;
            int rs = (pi < 0) ? sLds[row][px] : pi;
            int re = sLds[row][px + 1];
            int plane = row / 9, pyL = row % 9;
            int bin = plane * 4 + (pyL & 1) * 2 + (px & 1);
            bool blocked = false;
            for (int i = rs; i < re; i++) {
                int pos = atomicAdd(&cnt[bin], 1);
                if (pos >= CAPB) { pi = i; blocked = true; break; }
                unsigned e = (unsigned)entries[i];      // (pid<<1)|imp
                work[bin][pos] = (e << 8) | (unsigned)(pyL << 4) | (unsigned)px;
            }
            if (blocked) break;
            ci += 256; pi = -1;
        }
        if (ci < NCELL_R) notDone = 1;   // benign same-value race
        __syncthreads();
        int more = notDone;              // read before phase 2; reset happens after next barrier

        // ---- phase 2: tap-major, branchless inner loop ----
        for (int t = w; t < NTAP; t += 4) {
            int o0 = t / 9, r9 = t % 9, o1 = r9 / 3, o2 = r9 % 3;
            int bin = o0 * 4 + (o1 & 1) * 2 + ((o2 & 1) ^ 1);
            int nb = cnt[bin];
            if (nb > CAPB) nb = CAPB;
            if (nb == 0) continue;

            const float4* wp = (const float4*)(Wt + ((size_t)t * COUT + lane) * CIN);
            float4 w0 = wp[0], w1 = wp[1], w2 = wp[2], w3 = wp[3];
            float4 w4 = wp[4], w5 = wp[5], w6 = wp[6], w7 = wp[7];

#pragma unroll 2
            for (int j = 0; j < nb; j++) {
                unsigned e = work[bin][j];
                int pyL = (int)((e >> 4) & 15u);
                int px  = (int)(e & 15u);
                int yy = (pyL - o1) >> 1;              // parity guaranteed by bin
                int ox = (px + 1 - o2) >> 1;           // parity guaranteed by bin
                bool valid = ((unsigned)yy < (unsigned)TOY) & ((unsigned)ox < (unsigned)TOX);
                int cl = valid ? (yy * TOX + ox) : (TOY * TOX);   // dummy row absorbs misses
                int pid = (int)(e >> 9);

                const float4* fp = (const float4*)(feat + (size_t)pid * CIN);
                float4 f0 = fp[0], f1 = fp[1], f2 = fp[2], f3 = fp[3];
                float4 f4 = fp[4], f5 = fp[5], f6 = fp[6], f7 = fp[7];
                float a0 = 0.f, a1 = 0.f, a2 = 0.f, a3 = 0.f;
                a0 = fmaf(f0.x, w0.x, a0); a0 = fmaf(f0.y, w0.y, a0);
                a0 = fmaf(f0.z, w0.z, a0); a0 = fmaf(f0.w, w0.w, a0);
                a1 = fmaf(f1.x, w1.x, a1); a1 = fmaf(f1.y, w1.y, a1);
                a1 = fmaf(f1.z, w1.z, a1); a1 = fmaf(f1.w, w1.w, a1);
                a2 = fmaf(f2.x, w2.x, a2); a2 = fmaf(f2.y, w2.y, a2);
                a2 = fmaf(f2.z, w2.z, a2); a2 = fmaf(f2.w, w2.w, a2);
                a3 = fmaf(f3.x, w3.x, a3); a3 = fmaf(f3.y, w3.y, a3);
                a3 = fmaf(f3.z, w3.z, a3); a3 = fmaf(f3.w, w3.w, a3);
                a0 = fmaf(f4.x, w4.x, a0); a0 = fmaf(f4.y, w4.y, a0);
                a0 = fmaf(f4.z, w4.z, a0); a0 = fmaf(f4.w, w4.w, a0);
                a1 = fmaf(f5.x, w5.x, a1); a1 = fmaf(f5.y, w5.y, a1);
                a1 = fmaf(f5.z, w5.z, a1); a1 = fmaf(f5.w, w5.w, a1);
                a2 = fmaf(f6.x, w6.x, a2); a2 = fmaf(f6.y, w6.y, a2);
                a2 = fmaf(f6.z, w6.z, a2); a2 = fmaf(f6.w, w6.w, a2);
                a3 = fmaf(f7.x, w7.x, a3); a3 = fmaf(f7.y, w7.y, a3);
                a3 = fmaf(f7.z, w7.z, a3); a3 = fmaf(f7.w, w7.w, a3);

                atomicAdd(&accS[cl][lane], (a0 + a1) + (a2 + a3));
                if (valid && lane == 0 && (e & 0x100u)) keepS[cl] = 1;
            }
        }
        __syncthreads();
        if (!more) break;
    }

    // ---- epilogue: wave w stores cells w*8 .. w*8+7, coalesced ----
#pragma unroll
    for (int k = 0; k < 8; k++) {
        int cl = w * 8 + k;
        int oy = oyT + (cl >> 3);
        int ox = cl & 7;
        size_t cellG = (((size_t)bb * OD0 + oz) * OD1 + oy) * OD2 + ox;
        out[cellG * COUT + lane] = keepS[cl] ? accS[cl][lane] : 0.f;
    }
}

// ================= legacy scatter path (ws too small) =================

__global__ void __launch_bounds__(256)
scatter_kernel(const float* __restrict__ feat, const int* __restrict__ coors,
               const float* __restrict__ mask, const float* __restrict__ W,
               const int* __restrict__ state, float* __restrict__ out,
               int* __restrict__ keep, int n) {
    int gid = blockIdx.x * blockDim.x + threadIdx.x;
    int wave = gid >> 6;
    int lane = threadIdx.x & 63;
    if (wave >= n) return;

    const int4 c4 = ((const int4*)coors)[wave];
    int bb = c4.x, pz = c4.y, py = c4.z, px = c4.w;

    float thr = __uint_as_float((unsigned)state[0]);
    bool imp = mask[wave] >= thr;

    int oz[2], ozo[2], nz = 0;
    int oy[2], oyo[2], ny = 0;
    int ox[2], oxo[2], nx = 0;
#pragma unroll
    for (int o = 0; o < 3; o++) {
        int num = pz + 1 - o;
        if (num >= 0 && !(num & 1) && (num >> 1) < OD0) { oz[nz] = num >> 1; ozo[nz] = o; nz++; }
        num = py + 1 - o;
        if (num >= 0 && !(num & 1) && (num >> 1) < OD1) { oy[ny] = num >> 1; oyo[ny] = o; ny++; }
        num = px + 1 - o;
        if (num >= 0 && !(num & 1) && (num >> 1) < OD2) { ox[nx] = num >> 1; oxo[nx] = o; nx++; }
    }

    float f[CIN];
    const float4* fp = (const float4*)(feat + (size_t)wave * CIN);
#pragma unroll
    for (int j = 0; j < CIN / 4; j++) {
        float4 v = fp[j];
        f[4 * j + 0] = v.x; f[4 * j + 1] = v.y; f[4 * j + 2] = v.z; f[4 * j + 3] = v.w;
    }

    for (int a = 0; a < nz; a++)
        for (int b = 0; b < ny; b++)
            for (int c = 0; c < nx; c++) {
                int woff = ((ozo[a] * 3 + oyo[b]) * 3 + oxo[c]) * (CIN * COUT);
                const float* wcol = W + woff + lane;
                float acc = 0.f;
#pragma unroll
                for (int k = 0; k < CIN; k++) acc = fmaf(f[k], wcol[k * COUT], acc);
                int lin = ((bb * OD0 + oz[a]) * OD1 + oy[b]) * OD2 + ox[c];
                atomicAdd(out + (size_t)lin * COUT + lane, acc);
                if (imp && lane == 0) keep[lin] = 1;
            }
}

__global__ void finalize_kernel(float* __restrict__ out, const int* __restrict__ keep, int numOut) {
    int t = blockIdx.x * blockDim.x + threadIdx.x;
    if (t >= numOut * (COUT / 4)) return;
    int o = t >> 4;
    if (!keep[o]) ((float4*)out)[t] = make_float4(0.f, 0.f, 0.f, 0.f);
}

// ================= launcher =================

extern "C" void kernel_launch(void* const* d_in, const int* in_sizes, int n_in,
                              void* d_out, int out_size, void* d_ws, size_t ws_size,
                              hipStream_t stream) {
    const float* feat  = (const float*)d_in[0];   // (N, 32) f32
    const int*   coors = (const int*)d_in[1];     // (N, 4)  i32
    const float* mask  = (const float*)d_in[2];   // (N,)    f32
    const float* W     = (const float*)d_in[3];   // (3,3,3,32,64) f32

    int n = in_sizes[2];                 // N
    int numOut = out_size / COUT;        // 160000
    int rank = (int)(n * 0.5);           // int(N * PRUNING_RATIO)

    const int blk = 256;
    int gN = (n + blk - 1) / blk;

    char* ws = (char*)d_ws;

    // workspace layout
    size_t offHist    = 0;                                   // 4 x 256 ints = 4 KB
    size_t offState   = 4 * 256 * 4;                         // 64 B
    size_t offS       = offState + 64;                       // NCELLS ints = 5.12 MB (16B aligned)
    size_t offPart    = offS + (size_t)NCELLS * 4;           // 1250 ints (pad to 1280)
    size_t offEntries = offPart + 1280 * 4;                  // n ints
    size_t offWt      = offEntries + (size_t)n * 4;          // 27*64*32 f32
    size_t need       = offWt + (size_t)NTAP * CIN * COUT * 4;

    int* hist  = (int*)(ws + offHist);
    int* state = (int*)(ws + offState);

    if (ws_size >= need) {
        int*   S       = (int*)(ws + offS);
        int*   part    = (int*)(ws + offPart);
        int*   entries = (int*)(ws + offEntries);
        float* Wt      = (float*)(ws + offWt);

        void* args[] = { (void*)&mask, (void*)&coors, (void*)&W, (void*)&n, (void*)&rank,
                         (void*)&hist, (void*)&state, (void*)&S, (void*)&part,
                         (void*)&entries, (void*)&Wt };
        hipError_t ce = hipLaunchCooperativeKernel(
            reinterpret_cast<void*>(preamble_kernel),
            dim3(256), dim3(256), args, 0, stream);

        if (ce != hipSuccess) {
            // multi-launch fallback preamble
            hipMemsetAsync(ws, 0, offS + (size_t)NCELLS * 4, stream);
            hist0_fused_kernel<<<256, blk, 0, stream>>>(mask, coors, W, n, hist, S, Wt);
            select8_kernel<<<1, 256, 0, stream>>>(hist, state, 0, rank);
            for (int lvl = 1; lvl < 4; lvl++) {
                hist8_kernel<<<256, blk, 0, stream>>>(mask, n, lvl, state, hist + lvl * 256);
                select8_kernel<<<1, 256, 0, stream>>>(hist + lvl * 256, state, lvl, rank);
            }
            int nBlocksScan = NCELLS / 1024;                 // 1250
            scan_l0_kernel<<<nBlocksScan, 256, 0, stream>>>(S, part);
            scan_l1_kernel<<<1, 256, 0, stream>>>(part, nBlocksScan);
            scan_l2_kernel<<<nBlocksScan, 256, 0, stream>>>(S, part);
            scatter_points_kernel<<<gN, blk, 0, stream>>>(coors, mask, state, n, S, entries);
        }

        int nTiles = numOut / (TOY * TOX);                   // 5000
        conv_kernel<<<nTiles, 256, 0, stream>>>(feat, Wt, S, entries, (float*)d_out);
    } else {
        // legacy scatter path
        int* keep = (int*)(ws + offS);
        hipMemsetAsync(d_out, 0, (size_t)out_size * sizeof(float), stream);
        hipMemsetAsync(ws, 0, offS + (size_t)numOut * 4, stream);

        float* WtDummy = (float*)(ws + offS);   // unused scratch
        hist0_fused_kernel<<<256, blk, 0, stream>>>(mask, coors, W, n, hist,
                                                    (int*)(ws + offS), WtDummy);
        select8_kernel<<<1, 256, 0, stream>>>(hist, state, 0, rank);
        for (int lvl = 1; lvl < 4; lvl++) {
            hist8_kernel<<<256, blk, 0, stream>>>(mask, n, lvl, state, hist + lvl * 256);
            select8_kernel<<<1, 256, 0, stream>>>(hist + lvl * 256, state, lvl, rank);
        }

        long long threads = (long long)n * 64;
        int gScatter = (int)((threads + blk - 1) / blk);
        scatter_kernel<<<gScatter, blk, 0, stream>>>(feat, coors, mask, W, state,
                                                     (float*)d_out, keep, n);

        int fin = numOut * (COUT / 4);
        finalize_kernel<<<(fin + blk - 1) / blk, blk, 0, stream>>>((float*)d_out, keep, numOut);
    }
}

// Round 7
// 946.567 us; speedup vs baseline: 1.3795x; 1.3795x over previous
//
#include <hip/hip_runtime.h>

#define CIN 32
#define COUT 64
#define OD0 100
#define OD1 100
#define OD2 8
#define IZ 200
#define IY 200
#define IX 16
#define NTAP 27
#define NCELLS (2 * IZ * IY * IX)   // 1,280,000  (divisible by 1024)
#define TOY 4
#define TOX 8
#define NROW 27                      // 3 planes x 9 y-rows
#define NCELL_R (NROW * 16)          // 432 region cells
#define NBIN 54                      // (region row, px-parity)
#define CAPB 24                      // per-bin capacity (mean ~2.5)

// ---------- rank selection: four-level 8-bit radix (LDS-aggregated) ----------

// level 0 fused with CSR count + weight transpose (independent side jobs).
__global__ void hist0_fused_kernel(const float* __restrict__ mask, const int* __restrict__ coors,
                                   const float* __restrict__ W, int n,
                                   int* __restrict__ hist, int* __restrict__ S,
                                   float* __restrict__ Wt) {
    __shared__ int h[256];
    h[threadIdx.x] = 0;
    __syncthreads();
    for (int i = blockIdx.x * blockDim.x + threadIdx.x; i < n; i += gridDim.x * blockDim.x) {
        unsigned bits = __float_as_uint(mask[i]);   // mask in [0,1): uint order == float order
        atomicAdd(&h[bits >> 24], 1);
        const int4 c = ((const int4*)coors)[i];
        atomicAdd(&S[((c.x * IZ + c.y) * IY + c.z) * IX + c.w], 1);
    }
    for (int i = blockIdx.x * blockDim.x + threadIdx.x; i < NTAP * CIN * COUT;
         i += gridDim.x * blockDim.x) {
        int cout = i % COUT;
        int rest = i / COUT;
        int cin = rest % CIN;
        int tap = rest / CIN;
        Wt[((size_t)tap * COUT + cout) * CIN + cin] = W[i];
    }
    __syncthreads();
    int v = h[threadIdx.x];
    if (v) atomicAdd(&hist[threadIdx.x], v);
}

// mask-only level-0 histogram (legacy fallback path)
__global__ void hist0_simple_kernel(const float* __restrict__ mask, int n, int* __restrict__ hist) {
    __shared__ int h[256];
    h[threadIdx.x] = 0;
    __syncthreads();
    for (int i = blockIdx.x * blockDim.x + threadIdx.x; i < n; i += gridDim.x * blockDim.x) {
        unsigned bits = __float_as_uint(mask[i]);
        atomicAdd(&h[bits >> 24], 1);
    }
    __syncthreads();
    int v = h[threadIdx.x];
    if (v) atomicAdd(&hist[threadIdx.x], v);
}

__global__ void hist8_kernel(const float* __restrict__ mask, int n, int level,
                             const int* __restrict__ state, int* __restrict__ hist) {
    __shared__ int h[256];
    h[threadIdx.x] = 0;
    __syncthreads();
    unsigned pfx = (unsigned)state[0];
    int sh = 24 - 8 * level;
    for (int i = blockIdx.x * blockDim.x + threadIdx.x; i < n; i += gridDim.x * blockDim.x) {
        unsigned bits = __float_as_uint(mask[i]);
        if ((bits >> (sh + 8)) == pfx)
            atomicAdd(&h[(bits >> sh) & 0xFF], 1);
    }
    __syncthreads();
    int v = h[threadIdx.x];
    if (v) atomicAdd(&hist[threadIdx.x], v);
}

__global__ void select8_kernel(const int* __restrict__ hist, int* __restrict__ state,
                               int level, int rankConst) {
    __shared__ int sc[256];
    sc[threadIdx.x] = hist[threadIdx.x];
    __syncthreads();
    if (threadIdx.x == 0) {
        int rank = level ? state[1] : rankConst;
        unsigned pfx = level ? (unsigned)state[0] : 0u;
        int c = 0;
        for (int j = 0; j < 256; j++) {
            int hv = sc[j];
            if (rank < c + hv) {
                state[0] = (int)((pfx << 8) | (unsigned)j);
                state[1] = rank - c;
                break;
            }
            c += hv;
        }
    }
}

// ---------- CSR scan ----------

__global__ void scan_l0_kernel(int* __restrict__ S, int* __restrict__ partials) {
    __shared__ int ts[256];
    int tid = threadIdx.x;
    int4 v = ((int4*)S)[blockIdx.x * 256 + tid];
    int s1 = v.x + v.y, s2 = s1 + v.z, s3 = s2 + v.w;
    ts[tid] = s3;
    __syncthreads();
    for (int off = 1; off < 256; off <<= 1) {
        int t = (tid >= off) ? ts[tid - off] : 0;
        __syncthreads();
        ts[tid] += t;
        __syncthreads();
    }
    int excl = ts[tid] - s3;
    int4 o;
    o.x = excl; o.y = excl + v.x; o.z = excl + s1; o.w = excl + s2;
    ((int4*)S)[blockIdx.x * 256 + tid] = o;
    if (tid == 255) partials[blockIdx.x] = ts[255];
}

__global__ void scan_l1_kernel(int* __restrict__ partials, int nP) {
    __shared__ int sums[256];
    int tid = threadIdx.x;
    int per = (nP + 255) / 256;
    int lo = tid * per, hi = lo + per;
    if (hi > nP) hi = nP;
    int s = 0;
    for (int j = lo; j < hi; j++) s += partials[j];
    sums[tid] = s;
    __syncthreads();
    for (int off = 1; off < 256; off <<= 1) {
        int t = (tid >= off) ? sums[tid - off] : 0;
        __syncthreads();
        sums[tid] += t;
        __syncthreads();
    }
    int run = sums[tid] - s;
    for (int j = lo; j < hi; j++) { int v = partials[j]; partials[j] = run; run += v; }
}

__global__ void scan_l2_kernel(int* __restrict__ S, const int* __restrict__ partials) {
    int add = partials[blockIdx.x];
    if (add == 0) return;
    int4 v = ((int4*)S)[blockIdx.x * 256 + threadIdx.x];
    v.x += add; v.y += add; v.z += add; v.w += add;
    ((int4*)S)[blockIdx.x * 256 + threadIdx.x] = v;
}

// scatter point ids; S[c] becomes end-of-range (range c = [S[c-1], S[c]))
__global__ void scatter_points_kernel(const int* __restrict__ coors, const float* __restrict__ mask,
                                      const int* __restrict__ state, int n,
                                      int* __restrict__ S, int* __restrict__ entries) {
    int i = blockIdx.x * blockDim.x + threadIdx.x;
    if (i >= n) return;
    const int4 c = ((const int4*)coors)[i];
    int cell = ((c.x * IZ + c.y) * IY + c.z) * IX + c.w;
    float thr = __uint_as_float((unsigned)state[0]);
    int imp = (mask[i] >= thr) ? 1 : 0;
    int pos = atomicAdd(&S[cell], 1);
    entries[pos] = (i << 1) | imp;
}

// ================= main conv =================
// Block = 4x8 output tile at fixed (bb, oz); wave w owns output row yy=w
// (TOX=8 = full x-extent, so cl>>3 == w). A point at region row (plane,pyL)
// contributes to row w iff o1 = pyL-2w in {0,1,2}; its plane fixes o0; px
// parity fixes the o2 set. So: bin by (region row, px-parity) -> per
// (o1,plane,o2) group the wave scans one tiny bin at ~100% hit rate.
// Cells are wave-exclusive -> NO atomics anywhere; acc row in wave-private
// LDS (plain rmw, lane-consecutive = conflict-free); keep flags in a
// wave-uniform register bitmask. Weight column hoisted per group (regs).

__global__ void __launch_bounds__(256)
conv_kernel(const float* __restrict__ feat, const float* __restrict__ Wt,
            const int* __restrict__ S, const int* __restrict__ entries,
            float* __restrict__ out) {
    __shared__ float accS[TOY][TOX][COUT];        // 8 KB, wave-private rows
    __shared__ int   sLds[NROW][17];              // 1836 B
    __shared__ unsigned work[NBIN][CAPB];         // 5184 B
    __shared__ int   cnt[NBIN];
    __shared__ int   notDone;

    int tid = threadIdx.x;
    int w = tid >> 6;
    int lane = tid & 63;

    int tile = blockIdx.x;
    int oyT = (tile % (OD1 / TOY)) * TOY;
    int rest = tile / (OD1 / TOY);
    int oz = rest % OD0;
    int bb = rest / OD0;

    {   // zero own acc row (wave-local; no barrier needed)
        float4 z = make_float4(0.f, 0.f, 0.f, 0.f);
        float4* a4 = (float4*)&accS[w][0][0];     // 128 float4
        for (int i = lane; i < TOX * COUT / 4; i += 64) a4[i] = z;
    }

    // ---- phase 0: region S -> LDS (27 rows x 17, coalesced) ----
    for (int idx = tid; idx < NROW * 17; idx += 256) {
        int row = idx / 17, j = idx % 17;
        int plane = row / 9, pyL = row % 9;
        int pz = 2 * oz - 1 + plane;              // max 199, never clips high
        int py = 2 * oyT - 1 + pyL;               // max 199
        int v = 0;
        if (pz >= 0 && py >= 0) {
            int cellFlat = ((bb * IZ + pz) * IY + py) * IX + (j - 1);
            if (cellFlat >= 0) v = S[cellFlat];
        }
        sLds[row][j] = v;
    }

    int ci = tid;       // region cell, strided by 256
    int pi = -1;        // resume entry index (-1 = range start)
    int keepMask = 0;   // wave-uniform: bit ox = cell (w,ox) has important point

    for (;;) {
        if (tid < NBIN) cnt[tid] = 0;
        if (tid == 0) notDone = 0;
        __syncthreads();   // covers sLds init on first pass

        // ---- phase 1: enumerate points into 54 (row, px-parity) bins ----
        while (ci < NCELL_R) {
            int row = ci >> 4, px = ci & 15;
            int rs = (pi < 0) ? sLds[row][px] : pi;
            int re = sLds[row][px + 1];
            int bin = row * 2 + (px & 1);
            bool blocked = false;
            for (int i = rs; i < re; i++) {
                int pos = atomicAdd(&cnt[bin], 1);
                if (pos >= CAPB) { pi = i; blocked = true; break; }
                unsigned e = (unsigned)entries[i];       // (pid<<1)|imp
                work[bin][pos] = (e << 4) | (unsigned)px; // pid<<5 | imp<<4 | px
            }
            if (blocked) break;
            ci += 256; pi = -1;
        }
        if (ci < NCELL_R) notDone = 1;   // benign same-value race
        __syncthreads();
        int more = notDone;

        // ---- phase 2: wave w sweeps its 27 (o1,plane,o2) groups ----
        for (int o1 = 0; o1 < 3; o1++) {
            int pyL = 2 * w + o1;                       // 0..8
            for (int plane = 0; plane < 3; plane++) {
                int row = plane * 9 + pyL;
                for (int o2 = 0; o2 < 3; o2++) {
                    // o2=1 hits even px; o2=0/2 hit odd px
                    int bin = row * 2 + ((o2 == 1) ? 0 : 1);
                    int nb = cnt[bin];
                    if (nb > CAPB) nb = CAPB;
                    if (nb == 0) continue;
                    int tap = plane * 9 + o1 * 3 + o2;
                    const float4* wp = (const float4*)(Wt + ((size_t)tap * COUT + lane) * CIN);
                    float4 w0 = wp[0], w1 = wp[1], w2 = wp[2], w3 = wp[3];
                    float4 w4 = wp[4], w5 = wp[5], w6 = wp[6], w7 = wp[7];

#pragma unroll 2
                    for (int j = 0; j < nb; j++) {
                        unsigned e = work[bin][j];       // wave-uniform broadcast
                        int px = (int)(e & 15u);
                        int ox = (px + 1 - o2) >> 1;     // parity matches by bin
                        if ((unsigned)ox >= (unsigned)TOX) continue;  // only o2=0, px=15
                        int pid = (int)(e >> 5);

                        const float4* fp = (const float4*)(feat + (size_t)pid * CIN);
                        float4 f0 = fp[0], f1 = fp[1], f2 = fp[2], f3 = fp[3];
                        float4 f4 = fp[4], f5 = fp[5], f6 = fp[6], f7 = fp[7];
                        float a0 = 0.f, a1 = 0.f, a2 = 0.f, a3 = 0.f;
                        a0 = fmaf(f0.x, w0.x, a0); a0 = fmaf(f0.y, w0.y, a0);
                        a0 = fmaf(f0.z, w0.z, a0); a0 = fmaf(f0.w, w0.w, a0);
                        a1 = fmaf(f1.x, w1.x, a1); a1 = fmaf(f1.y, w1.y, a1);
                        a1 = fmaf(f1.z, w1.z, a1); a1 = fmaf(f1.w, w1.w, a1);
                        a2 = fmaf(f2.x, w2.x, a2); a2 = fmaf(f2.y, w2.y, a2);
                        a2 = fmaf(f2.z, w2.z, a2); a2 = fmaf(f2.w, w2.w, a2);
                        a3 = fmaf(f3.x, w3.x, a3); a3 = fmaf(f3.y, w3.y, a3);
                        a3 = fmaf(f3.z, w3.z, a3); a3 = fmaf(f3.w, w3.w, a3);
                        a0 = fmaf(f4.x, w4.x, a0); a0 = fmaf(f4.y, w4.y, a0);
                        a0 = fmaf(f4.z, w4.z, a0); a0 = fmaf(f4.w, w4.w, a0);
                        a1 = fmaf(f5.x, w5.x, a1); a1 = fmaf(f5.y, w5.y, a1);
                        a1 = fmaf(f5.z, w5.z, a1); a1 = fmaf(f5.w, w5.w, a1);
                        a2 = fmaf(f6.x, w6.x, a2); a2 = fmaf(f6.y, w6.y, a2);
                        a2 = fmaf(f6.z, w6.z, a2); a2 = fmaf(f6.w, w6.w, a2);
                        a3 = fmaf(f7.x, w7.x, a3); a3 = fmaf(f7.y, w7.y, a3);
                        a3 = fmaf(f7.z, w7.z, a3); a3 = fmaf(f7.w, w7.w, a3);

                        // wave-exclusive cell: plain LDS rmw, conflict-free
                        accS[w][ox][lane] += (a0 + a1) + (a2 + a3);
                        keepMask |= (int)((e >> 4) & 1u) << ox;
                    }
                }
            }
        }
        __syncthreads();
        if (!more) break;
    }

    // ---- epilogue: wave w stores its row, prune fused ----
    int oy = oyT + w;
#pragma unroll
    for (int ox = 0; ox < TOX; ox++) {
        size_t cellG = (((size_t)bb * OD0 + oz) * OD1 + oy) * OD2 + ox;
        float v = accS[w][ox][lane];
        out[cellG * COUT + lane] = ((keepMask >> ox) & 1) ? v : 0.f;
    }
}

// ================= legacy scatter path (ws too small) =================

__global__ void __launch_bounds__(256)
scatter_kernel(const float* __restrict__ feat, const int* __restrict__ coors,
               const float* __restrict__ mask, const float* __restrict__ W,
               const int* __restrict__ state, float* __restrict__ out,
               int* __restrict__ keep, int n) {
    int gid = blockIdx.x * blockDim.x + threadIdx.x;
    int wave = gid >> 6;
    int lane = threadIdx.x & 63;
    if (wave >= n) return;

    const int4 c4 = ((const int4*)coors)[wave];
    int bb = c4.x, pz = c4.y, py = c4.z, px = c4.w;

    float thr = __uint_as_float((unsigned)state[0]);
    bool imp = mask[wave] >= thr;

    int oz[2], ozo[2], nz = 0;
    int oy[2], oyo[2], ny = 0;
    int ox[2], oxo[2], nx = 0;
#pragma unroll
    for (int o = 0; o < 3; o++) {
        int num = pz + 1 - o;
        if (num >= 0 && !(num & 1) && (num >> 1) < OD0) { oz[nz] = num >> 1; ozo[nz] = o; nz++; }
        num = py + 1 - o;
        if (num >= 0 && !(num & 1) && (num >> 1) < OD1) { oy[ny] = num >> 1; oyo[ny] = o; ny++; }
        num = px + 1 - o;
        if (num >= 0 && !(num & 1) && (num >> 1) < OD2) { ox[nx] = num >> 1; oxo[nx] = o; nx++; }
    }

    float f[CIN];
    const float4* fp = (const float4*)(feat + (size_t)wave * CIN);
#pragma unroll
    for (int j = 0; j < CIN / 4; j++) {
        float4 v = fp[j];
        f[4 * j + 0] = v.x; f[4 * j + 1] = v.y; f[4 * j + 2] = v.z; f[4 * j + 3] = v.w;
    }

    for (int a = 0; a < nz; a++)
        for (int b = 0; b < ny; b++)
            for (int c = 0; c < nx; c++) {
                int woff = ((ozo[a] * 3 + oyo[b]) * 3 + oxo[c]) * (CIN * COUT);
                const float* wcol = W + woff + lane;
                float acc = 0.f;
#pragma unroll
                for (int k = 0; k < CIN; k++) acc = fmaf(f[k], wcol[k * COUT], acc);
                int lin = ((bb * OD0 + oz[a]) * OD1 + oy[b]) * OD2 + ox[c];
                atomicAdd(out + (size_t)lin * COUT + lane, acc);
                if (imp && lane == 0) keep[lin] = 1;
            }
}

__global__ void finalize_kernel(float* __restrict__ out, const int* __restrict__ keep, int numOut) {
    int t = blockIdx.x * blockDim.x + threadIdx.x;
    if (t >= numOut * (COUT / 4)) return;
    int o = t >> 4;
    if (!keep[o]) ((float4*)out)[t] = make_float4(0.f, 0.f, 0.f, 0.f);
}

// ================= launcher =================

extern "C" void kernel_launch(void* const* d_in, const int* in_sizes, int n_in,
                              void* d_out, int out_size, void* d_ws, size_t ws_size,
                              hipStream_t stream) {
    const float* feat  = (const float*)d_in[0];   // (N, 32) f32
    const int*   coors = (const int*)d_in[1];     // (N, 4)  i32
    const float* mask  = (const float*)d_in[2];   // (N,)    f32
    const float* W     = (const float*)d_in[3];   // (3,3,3,32,64) f32

    int n = in_sizes[2];                 // N
    int numOut = out_size / COUT;        // 160000
    int rank = (int)(n * 0.5);           // int(N * PRUNING_RATIO)

    const int blk = 256;
    int gN = (n + blk - 1) / blk;

    char* ws = (char*)d_ws;

    // workspace layout
    size_t offHist    = 0;                                   // 4 x 256 ints = 4 KB
    size_t offState   = 4 * 256 * 4;                         // 64 B
    size_t offS       = offState + 64;                       // NCELLS ints = 5.12 MB (16B aligned)
    size_t offPart    = offS + (size_t)NCELLS * 4;           // 1250 ints (pad to 1280)
    size_t offEntries = offPart + 1280 * 4;                  // n ints
    size_t offWt      = offEntries + (size_t)n * 4;          // 27*64*32 f32
    size_t need       = offWt + (size_t)NTAP * CIN * COUT * 4;

    int* hist  = (int*)(ws + offHist);
    int* state = (int*)(ws + offState);

    if (ws_size >= need) {
        int*   S       = (int*)(ws + offS);
        int*   part    = (int*)(ws + offPart);
        int*   entries = (int*)(ws + offEntries);
        float* Wt      = (float*)(ws + offWt);

        hipMemsetAsync(ws, 0, offS + (size_t)NCELLS * 4, stream);   // hists + state + S

        // level 0 (fused with CSR count + W transpose), then levels 1..3
        hist0_fused_kernel<<<256, blk, 0, stream>>>(mask, coors, W, n, hist, S, Wt);
        select8_kernel<<<1, 256, 0, stream>>>(hist, state, 0, rank);
        for (int lvl = 1; lvl < 4; lvl++) {
            hist8_kernel<<<256, blk, 0, stream>>>(mask, n, lvl, state, hist + lvl * 256);
            select8_kernel<<<1, 256, 0, stream>>>(hist + lvl * 256, state, lvl, rank);
        }

        int nBlocksScan = NCELLS / 1024;                     // 1250
        scan_l0_kernel<<<nBlocksScan, 256, 0, stream>>>(S, part);
        scan_l1_kernel<<<1, 256, 0, stream>>>(part, nBlocksScan);
        scan_l2_kernel<<<nBlocksScan, 256, 0, stream>>>(S, part);
        scatter_points_kernel<<<gN, blk, 0, stream>>>(coors, mask, state, n, S, entries);

        int nTiles = numOut / (TOY * TOX);                   // 5000
        conv_kernel<<<nTiles, 256, 0, stream>>>(feat, Wt, S, entries, (float*)d_out);
    } else {
        // legacy scatter path (correct, self-contained)
        int* keep = (int*)(ws + offS);
        hipMemsetAsync(d_out, 0, (size_t)out_size * sizeof(float), stream);
        hipMemsetAsync(ws, 0, offS + (size_t)numOut * 4, stream);

        hist0_simple_kernel<<<256, blk, 0, stream>>>(mask, n, hist);
        select8_kernel<<<1, 256, 0, stream>>>(hist, state, 0, rank);
        for (int lvl = 1; lvl < 4; lvl++) {
            hist8_kernel<<<256, blk, 0, stream>>>(mask, n, lvl, state, hist + lvl * 256);
            select8_kernel<<<1, 256, 0, stream>>>(hist + lvl * 256, state, lvl, rank);
        }

        long long threads = (long long)n * 64;
        int gScatter = (int)((threads + blk - 1) / blk);
        scatter_kernel<<<gScatter, blk, 0, stream>>>(feat, coors, mask, W, state,
                                                     (float*)d_out, keep, n);

        int fin = numOut * (COUT / 4);
        finalize_kernel<<<(fin + blk - 1) / blk, blk, 0, stream>>>((float*)d_out, keep, numOut);
    }
}

// Round 8
// 922.067 us; speedup vs baseline: 1.4162x; 1.0266x over previous
//
#include <hip/hip_runtime.h>

#define CIN 32
#define COUT 64
#define OD0 100
#define OD1 100
#define OD2 8
#define IZ 200
#define IY 200
#define IX 16
#define NTAP 27
#define NCELLS (2 * IZ * IY * IX)   // 1,280,000  (divisible by 1024)
#define TOY 4
#define TOX 8
#define NROW 27                      // 3 planes x 9 y-rows
#define NCELL_R (NROW * 16)          // 432 region cells
#define CAPB 384                     // per-bin worklist capacity (r4-proven)

// ---------- fused: level-0 histogram + CSR count + W transpose ----------

__global__ void hist0_fused_kernel(const float* __restrict__ mask, const int* __restrict__ coors,
                                   const float* __restrict__ W, int n,
                                   int* __restrict__ hist, int* __restrict__ S,
                                   float* __restrict__ Wt) {
    __shared__ int h[256];
    h[threadIdx.x] = 0;
    __syncthreads();
    for (int i = blockIdx.x * blockDim.x + threadIdx.x; i < n; i += gridDim.x * blockDim.x) {
        unsigned bits = __float_as_uint(mask[i]);   // mask in [0,1): uint order == float order
        atomicAdd(&h[bits >> 24], 1);
        const int4 c = ((const int4*)coors)[i];
        atomicAdd(&S[((c.x * IZ + c.y) * IY + c.z) * IX + c.w], 1);
    }
    for (int i = blockIdx.x * blockDim.x + threadIdx.x; i < NTAP * CIN * COUT;
         i += gridDim.x * blockDim.x) {
        int cout = i % COUT;
        int rest = i / COUT;
        int cin = rest % CIN;
        int tap = rest / CIN;
        Wt[((size_t)tap * COUT + cout) * CIN + cin] = W[i];
    }
    __syncthreads();
    int v = h[threadIdx.x];
    if (v) atomicAdd(&hist[threadIdx.x], v);
}

// ---------- single-block 4-level rank selection ----------
// Level 0 from precomputed hist; pass A scans mask once (collect matching
// values to global scratch); passes B/C work on scratch / LDS candidates.
// Result: state[0] = full 32-bit float bits of the rank-th smallest value.

__global__ void __launch_bounds__(1024)
sel4_kernel(const float* __restrict__ mask, int n, const int* __restrict__ hist0,
            int rank0, int* __restrict__ state, unsigned* __restrict__ scratch) {
    __shared__ int h[256];
    __shared__ int cand[4096];
    __shared__ int scnt;
    __shared__ int sel;
    __shared__ int rnk;
    int tid = threadIdx.x;

    // select level 0
    if (tid == 0) {
        int c = 0;
        for (int j = 0; j < 256; j++) {
            int hv = hist0[j];
            if (rank0 < c + hv) { sel = j; rnk = rank0 - c; break; }
            c += hv;
        }
    }
    __syncthreads();
    if (tid < 256) h[tid] = 0;
    if (tid == 0) scnt = 0;
    __syncthreads();
    unsigned p0 = (unsigned)sel;

    // pass A: level-1 hist + collect matching values to scratch
    for (int i = tid; i < n; i += 1024) {
        unsigned bits = __float_as_uint(mask[i]);
        if ((bits >> 24) == p0) {
            atomicAdd(&h[(bits >> 16) & 0xFF], 1);
            int pos = atomicAdd(&scnt, 1);
            scratch[pos] = bits;
        }
    }
    __syncthreads();
    int nScratch = scnt;
    if (tid == 0) {
        int c = 0, r = rnk;
        for (int j = 0; j < 256; j++) {
            int hv = h[j];
            if (r < c + hv) { sel = (sel << 8) | j; rnk = r - c; break; }
            c += hv;
        }
    }
    __syncthreads();
    if (tid < 256) h[tid] = 0;
    if (tid == 0) scnt = 0;
    __syncthreads();
    unsigned p1 = (unsigned)sel;

    // pass B: level-2 hist over scratch + collect candidates to LDS
    for (int i = tid; i < nScratch; i += 1024) {
        unsigned bits = scratch[i];
        if ((bits >> 16) == p1) {
            atomicAdd(&h[(bits >> 8) & 0xFF], 1);
            int pos = atomicAdd(&scnt, 1);
            if (pos < 4096) cand[pos] = (int)bits;
        }
    }
    __syncthreads();
    int nCand = scnt;
    bool useLds = (nCand <= 4096);
    if (tid == 0) {
        int c = 0, r = rnk;
        for (int j = 0; j < 256; j++) {
            int hv = h[j];
            if (r < c + hv) { sel = (sel << 8) | j; rnk = r - c; break; }
            c += hv;
        }
    }
    __syncthreads();
    if (tid < 256) h[tid] = 0;
    __syncthreads();
    unsigned p2 = (unsigned)sel;

    // pass C: level-3 hist
    if (useLds) {
        for (int i = tid; i < nCand; i += 1024) {
            unsigned bits = (unsigned)cand[i];
            if ((bits >> 8) == p2) atomicAdd(&h[bits & 0xFF], 1);
        }
    } else {
        for (int i = tid; i < nScratch; i += 1024) {
            unsigned bits = scratch[i];
            if ((bits >> 8) == p2) atomicAdd(&h[bits & 0xFF], 1);
        }
    }
    __syncthreads();
    if (tid == 0) {
        int c = 0, r = rnk;
        for (int j = 0; j < 256; j++) {
            int hv = h[j];
            if (r < c + hv) { sel = (sel << 8) | j; break; }
            c += hv;
        }
        state[0] = sel;     // full threshold bits
    }
}

// ---------- CSR scan ----------

__global__ void scan_l0_kernel(int* __restrict__ S, int* __restrict__ partials) {
    __shared__ int ts[256];
    int tid = threadIdx.x;
    int4 v = ((int4*)S)[blockIdx.x * 256 + tid];
    int s1 = v.x + v.y, s2 = s1 + v.z, s3 = s2 + v.w;
    ts[tid] = s3;
    __syncthreads();
    for (int off = 1; off < 256; off <<= 1) {
        int t = (tid >= off) ? ts[tid - off] : 0;
        __syncthreads();
        ts[tid] += t;
        __syncthreads();
    }
    int excl = ts[tid] - s3;
    int4 o;
    o.x = excl; o.y = excl + v.x; o.z = excl + s1; o.w = excl + s2;
    ((int4*)S)[blockIdx.x * 256 + tid] = o;
    if (tid == 255) partials[blockIdx.x] = ts[255];
}

__global__ void scan_l1_kernel(int* __restrict__ partials, int nP) {
    __shared__ int sums[256];
    int tid = threadIdx.x;
    int per = (nP + 255) / 256;
    int lo = tid * per, hi = lo + per;
    if (hi > nP) hi = nP;
    int s = 0;
    for (int j = lo; j < hi; j++) s += partials[j];
    sums[tid] = s;
    __syncthreads();
    for (int off = 1; off < 256; off <<= 1) {
        int t = (tid >= off) ? sums[tid - off] : 0;
        __syncthreads();
        sums[tid] += t;
        __syncthreads();
    }
    int run = sums[tid] - s;
    for (int j = lo; j < hi; j++) { int v = partials[j]; partials[j] = run; run += v; }
}

__global__ void scan_l2_kernel(int* __restrict__ S, const int* __restrict__ partials) {
    int add = partials[blockIdx.x];
    if (add == 0) return;
    int4 v = ((int4*)S)[blockIdx.x * 256 + threadIdx.x];
    v.x += add; v.y += add; v.z += add; v.w += add;
    ((int4*)S)[blockIdx.x * 256 + threadIdx.x] = v;
}

// scatter point ids; S[c] becomes end-of-range (range c = [S[c-1], S[c]))
__global__ void scatter_points_kernel(const int* __restrict__ coors, const float* __restrict__ mask,
                                      const int* __restrict__ state, int n,
                                      int* __restrict__ S, int* __restrict__ entries) {
    int i = blockIdx.x * blockDim.x + threadIdx.x;
    if (i >= n) return;
    const int4 c = ((const int4*)coors)[i];
    int cell = ((c.x * IZ + c.y) * IY + c.z) * IX + c.w;
    float thr = __uint_as_float((unsigned)state[0]);
    int imp = (mask[i] >= thr) ? 1 : 0;
    int pos = atomicAdd(&S[cell], 1);
    entries[pos] = (i << 1) | imp;
}

// ---------- main conv (r4-exact: measured 556 us) ----------
// Block = 4x8 output tile at fixed (bb, oz). Input region = 3 planes x 9 rows x 16.
// Phase 0: region S -> LDS. Phase 1: points into 6 (plane, y-parity) bins.
// Phase 2: taps round-robin over 4 waves; weight column in regs; scan bin;
// hits: global feat load + 32 fma + LDS atomic into acc tile.

__global__ void __launch_bounds__(256)
conv_kernel(const float* __restrict__ feat, const float* __restrict__ Wt,
            const int* __restrict__ S, const int* __restrict__ entries,
            float* __restrict__ out) {
    __shared__ float accS[TOY * TOX][COUT];       // 8 KB
    __shared__ int   keepS[TOY * TOX];
    __shared__ int   sLds[NROW][17];              // 1836 B
    __shared__ unsigned work[6][CAPB];            // 9 KB
    __shared__ int   cnt[6];
    __shared__ int   notDone;

    int tid = threadIdx.x;
    int w = tid >> 6;
    int lane = tid & 63;

    int tile = blockIdx.x;
    int oyT = (tile % (OD1 / TOY)) * TOY;
    int rest = tile / (OD1 / TOY);
    int oz = rest % OD0;
    int bb = rest / OD0;

    // zero accumulators
    {
        float4 z = make_float4(0.f, 0.f, 0.f, 0.f);
        float4* a4 = (float4*)&accS[0][0];
        a4[tid] = z;
        a4[tid + 256] = z;
        if (tid < TOY * TOX) keepS[tid] = 0;
    }

    // ---- phase 0: region S -> LDS (27 rows x 17 values, coalesced) ----
    for (int idx = tid; idx < NROW * 17; idx += 256) {
        int row = idx / 17, j = idx % 17;
        int plane = row / 9, pyL = row % 9;
        int pz = 2 * oz - 1 + plane;
        int py = 2 * oyT - 1 + pyL;
        int v = 0;
        if (pz >= 0 && py >= 0) {                 // upper bounds never exceeded
            int cellFlat = ((bb * IZ + pz) * IY + py) * IX + (j - 1);
            if (cellFlat >= 0) v = S[cellFlat];
        }
        sLds[row][j] = v;
    }
    __syncthreads();

    // per-thread enumeration state (overflow-safe resume)
    int myCl[2]; int nMy = 0;
    for (int cl = tid; cl < NCELL_R; cl += 256) myCl[nMy++] = cl;
    int ci = 0;
    int pi = -1;    // next global entry index within current cell; -1 = from range start

    for (;;) {
        if (tid < 6) cnt[tid] = 0;
        if (tid == 0) notDone = 0;
        __syncthreads();

        // ---- phase 1: enumerate points into 6 bins ----
        while (ci < nMy) {
            int cl = myCl[ci];
            int row = cl >> 4, px = cl & 15;
            int rs = (pi < 0) ? sLds[row][px] : pi;
            int re = sLds[row][px + 1];
            int plane = row / 9, pyL = row % 9;
            int bin = plane * 2 + (pyL & 1);
            bool blocked = false;
            for (int i = rs; i < re; i++) {
                int pos = atomicAdd(&cnt[bin], 1);
                if (pos >= CAPB) { pi = i; blocked = true; break; }
                int e = entries[i];
                work[bin][pos] = ((unsigned)(e >> 1) << 9) | (unsigned)((e & 1) << 8)
                               | (unsigned)(pyL << 4) | (unsigned)px;
            }
            if (blocked) break;
            ci++; pi = -1;
        }
        if (ci < nMy) notDone = 1;   // benign same-value race
        __syncthreads();

        // ---- phase 2: tap-major compute, weights in registers ----
        for (int t = w; t < NTAP; t += 4) {
            int o0 = t / 9, r9 = t % 9, o1 = r9 / 3, o2 = r9 % 3;
            int bin = o0 * 2 + (o1 & 1);
            int nb = cnt[bin];
            if (nb > CAPB) nb = CAPB;
            if (nb == 0) continue;

            const float4* wp = (const float4*)(Wt + ((size_t)t * COUT + lane) * CIN);
            float4 w0 = wp[0], w1 = wp[1], w2 = wp[2], w3 = wp[3];
            float4 w4 = wp[4], w5 = wp[5], w6 = wp[6], w7 = wp[7];

            for (int j = 0; j < nb; j++) {
                unsigned e = work[bin][j];
                int pyL = (int)((e >> 4) & 15u);
                int px  = (int)(e & 15u);
                int yy = (pyL - o1) >> 1;              // parity guaranteed by bin
                if ((unsigned)yy >= (unsigned)TOY) continue;
                int dx = px + 1 - o2;
                if (dx & 1) continue;
                int ox = dx >> 1;
                if ((unsigned)ox >= (unsigned)TOX) continue;

                int pid = (int)(e >> 9);
                const float4* fp = (const float4*)(feat + (size_t)pid * CIN);
                float4 f0 = fp[0], f1 = fp[1], f2 = fp[2], f3 = fp[3];
                float4 f4 = fp[4], f5 = fp[5], f6 = fp[6], f7 = fp[7];
                float a0 = 0.f, a1 = 0.f, a2 = 0.f, a3 = 0.f;
                a0 = fmaf(f0.x, w0.x, a0); a0 = fmaf(f0.y, w0.y, a0);
                a0 = fmaf(f0.z, w0.z, a0); a0 = fmaf(f0.w, w0.w, a0);
                a1 = fmaf(f1.x, w1.x, a1); a1 = fmaf(f1.y, w1.y, a1);
                a1 = fmaf(f1.z, w1.z, a1); a1 = fmaf(f1.w, w1.w, a1);
                a2 = fmaf(f2.x, w2.x, a2); a2 = fmaf(f2.y, w2.y, a2);
                a2 = fmaf(f2.z, w2.z, a2); a2 = fmaf(f2.w, w2.w, a2);
                a3 = fmaf(f3.x, w3.x, a3); a3 = fmaf(f3.y, w3.y, a3);
                a3 = fmaf(f3.z, w3.z, a3); a3 = fmaf(f3.w, w3.w, a3);
                a0 = fmaf(f4.x, w4.x, a0); a0 = fmaf(f4.y, w4.y, a0);
                a0 = fmaf(f4.z, w4.z, a0); a0 = fmaf(f4.w, w4.w, a0);
                a1 = fmaf(f5.x, w5.x, a1); a1 = fmaf(f5.y, w5.y, a1);
                a1 = fmaf(f5.z, w5.z, a1); a1 = fmaf(f5.w, w5.w, a1);
                a2 = fmaf(f6.x, w6.x, a2); a2 = fmaf(f6.y, w6.y, a2);
                a2 = fmaf(f6.z, w6.z, a2); a2 = fmaf(f6.w, w6.w, a2);
                a3 = fmaf(f7.x, w7.x, a3); a3 = fmaf(f7.y, w7.y, a3);
                a3 = fmaf(f7.z, w7.z, a3); a3 = fmaf(f7.w, w7.w, a3);

                int cl = yy * TOX + ox;
                atomicAdd(&accS[cl][lane], (a0 + a1) + (a2 + a3));
                if (lane == 0 && (e & 0x100u)) keepS[cl] = 1;
            }
        }
        __syncthreads();
        if (!notDone) break;
    }

    // ---- epilogue: wave w stores cells w*8 .. w*8+7, coalesced ----
#pragma unroll
    for (int k = 0; k < 8; k++) {
        int cl = w * 8 + k;
        int oy = oyT + (cl >> 3);
        int ox = cl & 7;
        size_t cellG = (((size_t)bb * OD0 + oz) * OD1 + oy) * OD2 + ox;
        out[cellG * COUT + lane] = keepS[cl] ? accS[cl][lane] : 0.f;
    }
}

// ================= legacy scatter path (ws too small) =================

__global__ void hist0_simple_kernel(const float* __restrict__ mask, int n, int* __restrict__ hist) {
    __shared__ int h[256];
    h[threadIdx.x] = 0;
    __syncthreads();
    for (int i = blockIdx.x * blockDim.x + threadIdx.x; i < n; i += gridDim.x * blockDim.x) {
        unsigned bits = __float_as_uint(mask[i]);
        atomicAdd(&h[bits >> 24], 1);
    }
    __syncthreads();
    int v = h[threadIdx.x];
    if (v) atomicAdd(&hist[threadIdx.x], v);
}

__global__ void hist8_kernel(const float* __restrict__ mask, int n, int level,
                             const int* __restrict__ state, int* __restrict__ hist) {
    __shared__ int h[256];
    h[threadIdx.x] = 0;
    __syncthreads();
    unsigned pfx = (unsigned)state[0];
    int sh = 24 - 8 * level;
    for (int i = blockIdx.x * blockDim.x + threadIdx.x; i < n; i += gridDim.x * blockDim.x) {
        unsigned bits = __float_as_uint(mask[i]);
        if ((bits >> (sh + 8)) == pfx)
            atomicAdd(&h[(bits >> sh) & 0xFF], 1);
    }
    __syncthreads();
    int v = h[threadIdx.x];
    if (v) atomicAdd(&hist[threadIdx.x], v);
}

__global__ void select8_kernel(const int* __restrict__ hist, int* __restrict__ state,
                               int level, int rankConst) {
    __shared__ int sc[256];
    sc[threadIdx.x] = hist[threadIdx.x];
    __syncthreads();
    if (threadIdx.x == 0) {
        int rank = level ? state[1] : rankConst;
        unsigned pfx = level ? (unsigned)state[0] : 0u;
        int c = 0;
        for (int j = 0; j < 256; j++) {
            int hv = sc[j];
            if (rank < c + hv) {
                state[0] = (int)((pfx << 8) | (unsigned)j);
                state[1] = rank - c;
                break;
            }
            c += hv;
        }
    }
}

__global__ void __launch_bounds__(256)
scatter_kernel(const float* __restrict__ feat, const int* __restrict__ coors,
               const float* __restrict__ mask, const float* __restrict__ W,
               const int* __restrict__ state, float* __restrict__ out,
               int* __restrict__ keep, int n) {
    int gid = blockIdx.x * blockDim.x + threadIdx.x;
    int wave = gid >> 6;
    int lane = threadIdx.x & 63;
    if (wave >= n) return;

    const int4 c4 = ((const int4*)coors)[wave];
    int bb = c4.x, pz = c4.y, py = c4.z, px = c4.w;

    float thr = __uint_as_float((unsigned)state[0]);
    bool imp = mask[wave] >= thr;

    int oz[2], ozo[2], nz = 0;
    int oy[2], oyo[2], ny = 0;
    int ox[2], oxo[2], nx = 0;
#pragma unroll
    for (int o = 0; o < 3; o++) {
        int num = pz + 1 - o;
        if (num >= 0 && !(num & 1) && (num >> 1) < OD0) { oz[nz] = num >> 1; ozo[nz] = o; nz++; }
        num = py + 1 - o;
        if (num >= 0 && !(num & 1) && (num >> 1) < OD1) { oy[ny] = num >> 1; oyo[ny] = o; ny++; }
        num = px + 1 - o;
        if (num >= 0 && !(num & 1) && (num >> 1) < OD2) { ox[nx] = num >> 1; oxo[nx] = o; nx++; }
    }

    float f[CIN];
    const float4* fp = (const float4*)(feat + (size_t)wave * CIN);
#pragma unroll
    for (int j = 0; j < CIN / 4; j++) {
        float4 v = fp[j];
        f[4 * j + 0] = v.x; f[4 * j + 1] = v.y; f[4 * j + 2] = v.z; f[4 * j + 3] = v.w;
    }

    for (int a = 0; a < nz; a++)
        for (int b = 0; b < ny; b++)
            for (int c = 0; c < nx; c++) {
                int woff = ((ozo[a] * 3 + oyo[b]) * 3 + oxo[c]) * (CIN * COUT);
                const float* wcol = W + woff + lane;
                float acc = 0.f;
#pragma unroll
                for (int k = 0; k < CIN; k++) acc = fmaf(f[k], wcol[k * COUT], acc);
                int lin = ((bb * OD0 + oz[a]) * OD1 + oy[b]) * OD2 + ox[c];
                atomicAdd(out + (size_t)lin * COUT + lane, acc);
                if (imp && lane == 0) keep[lin] = 1;
            }
}

__global__ void finalize_kernel(float* __restrict__ out, const int* __restrict__ keep, int numOut) {
    int t = blockIdx.x * blockDim.x + threadIdx.x;
    if (t >= numOut * (COUT / 4)) return;
    int o = t >> 4;
    if (!keep[o]) ((float4*)out)[t] = make_float4(0.f, 0.f, 0.f, 0.f);
}

// ================= launcher =================

extern "C" void kernel_launch(void* const* d_in, const int* in_sizes, int n_in,
                              void* d_out, int out_size, void* d_ws, size_t ws_size,
                              hipStream_t stream) {
    const float* feat  = (const float*)d_in[0];   // (N, 32) f32
    const int*   coors = (const int*)d_in[1];     // (N, 4)  i32
    const float* mask  = (const float*)d_in[2];   // (N,)    f32
    const float* W     = (const float*)d_in[3];   // (3,3,3,32,64) f32

    int n = in_sizes[2];                 // N
    int numOut = out_size / COUT;        // 160000
    int rank = (int)(n * 0.5);           // int(N * PRUNING_RATIO)

    const int blk = 256;
    int gN = (n + blk - 1) / blk;

    char* ws = (char*)d_ws;

    // workspace layout
    size_t offHist    = 0;                                   // 4 x 256 ints = 4 KB
    size_t offState   = 4 * 256 * 4;                         // 64 B
    size_t offS       = offState + 64;                       // NCELLS ints = 5.12 MB (16B aligned)
    size_t offPart    = offS + (size_t)NCELLS * 4;           // 1250 ints (pad to 1280)
    size_t offEntries = offPart + 1280 * 4;                  // n ints (also sel4 scratch)
    size_t offWt      = offEntries + (size_t)n * 4;          // 27*64*32 f32
    size_t need       = offWt + (size_t)NTAP * CIN * COUT * 4;

    int* hist  = (int*)(ws + offHist);
    int* state = (int*)(ws + offState);

    if (ws_size >= need) {
        int*   S       = (int*)(ws + offS);
        int*   part    = (int*)(ws + offPart);
        int*   entries = (int*)(ws + offEntries);
        float* Wt      = (float*)(ws + offWt);

        hipMemsetAsync(ws, 0, offS + (size_t)NCELLS * 4, stream);   // hist + state + S

        // level-0 hist + CSR count + W transpose (one kernel)
        hist0_fused_kernel<<<256, blk, 0, stream>>>(mask, coors, W, n, hist, S, Wt);
        // levels 1-3 in a single-block kernel (entries reused as scratch)
        sel4_kernel<<<1, 1024, 0, stream>>>(mask, n, hist, rank, state, (unsigned*)entries);

        int nBlocksScan = NCELLS / 1024;                     // 1250
        scan_l0_kernel<<<nBlocksScan, 256, 0, stream>>>(S, part);
        scan_l1_kernel<<<1, 256, 0, stream>>>(part, nBlocksScan);
        scan_l2_kernel<<<nBlocksScan, 256, 0, stream>>>(S, part);
        scatter_points_kernel<<<gN, blk, 0, stream>>>(coors, mask, state, n, S, entries);

        int nTiles = numOut / (TOY * TOX);                   // 5000
        conv_kernel<<<nTiles, 256, 0, stream>>>(feat, Wt, S, entries, (float*)d_out);
    } else {
        // legacy scatter path (self-contained)
        int* keep = (int*)(ws + offS);
        hipMemsetAsync(d_out, 0, (size_t)out_size * sizeof(float), stream);
        hipMemsetAsync(ws, 0, offS + (size_t)numOut * 4, stream);

        hist0_simple_kernel<<<256, blk, 0, stream>>>(mask, n, hist);
        select8_kernel<<<1, 256, 0, stream>>>(hist, state, 0, rank);
        for (int lvl = 1; lvl < 4; lvl++) {
            hist8_kernel<<<256, blk, 0, stream>>>(mask, n, lvl, state, hist + lvl * 256);
            select8_kernel<<<1, 256, 0, stream>>>(hist + lvl * 256, state, lvl, rank);
        }

        long long threads = (long long)n * 64;
        int gScatter = (int)((threads + blk - 1) / blk);
        scatter_kernel<<<gScatter, blk, 0, stream>>>(feat, coors, mask, W, state,
                                                     (float*)d_out, keep, n);

        int fin = numOut * (COUT / 4);
        finalize_kernel<<<(fin + blk - 1) / blk, blk, 0, stream>>>((float*)d_out, keep, numOut);
    }
}

// Round 9
// 733.570 us; speedup vs baseline: 1.7801x; 1.2570x over previous
//
#include <hip/hip_runtime.h>

#define CIN 32
#define COUT 64
#define OD0 100
#define OD1 100
#define OD2 8
#define IZ 200
#define IY 200
#define IX 16
#define NTAP 27
#define NCELLS (2 * IZ * IY * IX)   // 1,280,000  (divisible by 1024)
#define TOY 4
#define TOX 8
#define NROW 27                      // 3 planes x 9 y-rows
#define NCELL_R (NROW * 16)          // 432 region cells
#define CAPB 384                     // per-bin worklist capacity (r4-proven)

// ---------- fused: level-0 histogram + CSR count + W transpose ----------

__global__ void hist0_fused_kernel(const float* __restrict__ mask, const int* __restrict__ coors,
                                   const float* __restrict__ W, int n,
                                   int* __restrict__ hist, int* __restrict__ S,
                                   float* __restrict__ Wt) {
    __shared__ int h[256];
    h[threadIdx.x] = 0;
    __syncthreads();
    for (int i = blockIdx.x * blockDim.x + threadIdx.x; i < n; i += gridDim.x * blockDim.x) {
        unsigned bits = __float_as_uint(mask[i]);   // mask in [0,1): uint order == float order
        atomicAdd(&h[bits >> 24], 1);
        const int4 c = ((const int4*)coors)[i];
        atomicAdd(&S[((c.x * IZ + c.y) * IY + c.z) * IX + c.w], 1);
    }
    for (int i = blockIdx.x * blockDim.x + threadIdx.x; i < NTAP * CIN * COUT;
         i += gridDim.x * blockDim.x) {
        int cout = i % COUT;
        int rest = i / COUT;
        int cin = rest % CIN;
        int tap = rest / CIN;
        Wt[((size_t)tap * COUT + cout) * CIN + cin] = W[i];
    }
    __syncthreads();
    int v = h[threadIdx.x];
    if (v) atomicAdd(&hist[threadIdx.x], v);
}

// ---------- rank selection: 8-bit radix levels (multi-block, r4-proven) ----------

__global__ void hist8_kernel(const float* __restrict__ mask, int n, int level,
                             const int* __restrict__ state, int* __restrict__ hist) {
    __shared__ int h[256];
    h[threadIdx.x] = 0;
    __syncthreads();
    unsigned pfx = (unsigned)state[0];
    int sh = 24 - 8 * level;
    for (int i = blockIdx.x * blockDim.x + threadIdx.x; i < n; i += gridDim.x * blockDim.x) {
        unsigned bits = __float_as_uint(mask[i]);
        if ((bits >> (sh + 8)) == pfx)
            atomicAdd(&h[(bits >> sh) & 0xFF], 1);
    }
    __syncthreads();
    int v = h[threadIdx.x];
    if (v) atomicAdd(&hist[threadIdx.x], v);
}

__global__ void select8_kernel(const int* __restrict__ hist, int* __restrict__ state,
                               int level, int rankConst) {
    __shared__ int sc[256];
    sc[threadIdx.x] = hist[threadIdx.x];
    __syncthreads();
    if (threadIdx.x == 0) {
        int rank = level ? state[1] : rankConst;
        unsigned pfx = level ? (unsigned)state[0] : 0u;
        int c = 0;
        for (int j = 0; j < 256; j++) {
            int hv = sc[j];
            if (rank < c + hv) {
                state[0] = (int)((pfx << 8) | (unsigned)j);
                state[1] = rank - c;
                break;
            }
            c += hv;
        }
    }
}

// ---------- CSR scan ----------

__global__ void scan_l0_kernel(int* __restrict__ S, int* __restrict__ partials) {
    __shared__ int ts[256];
    int tid = threadIdx.x;
    int4 v = ((int4*)S)[blockIdx.x * 256 + tid];
    int s1 = v.x + v.y, s2 = s1 + v.z, s3 = s2 + v.w;
    ts[tid] = s3;
    __syncthreads();
    for (int off = 1; off < 256; off <<= 1) {
        int t = (tid >= off) ? ts[tid - off] : 0;
        __syncthreads();
        ts[tid] += t;
        __syncthreads();
    }
    int excl = ts[tid] - s3;
    int4 o;
    o.x = excl; o.y = excl + v.x; o.z = excl + s1; o.w = excl + s2;
    ((int4*)S)[blockIdx.x * 256 + tid] = o;
    if (tid == 255) partials[blockIdx.x] = ts[255];
}

__global__ void scan_l1_kernel(int* __restrict__ partials, int nP) {
    __shared__ int sums[256];
    int tid = threadIdx.x;
    int per = (nP + 255) / 256;
    int lo = tid * per, hi = lo + per;
    if (hi > nP) hi = nP;
    int s = 0;
    for (int j = lo; j < hi; j++) s += partials[j];
    sums[tid] = s;
    __syncthreads();
    for (int off = 1; off < 256; off <<= 1) {
        int t = (tid >= off) ? sums[tid - off] : 0;
        __syncthreads();
        sums[tid] += t;
        __syncthreads();
    }
    int run = sums[tid] - s;
    for (int j = lo; j < hi; j++) { int v = partials[j]; partials[j] = run; run += v; }
}

__global__ void scan_l2_kernel(int* __restrict__ S, const int* __restrict__ partials) {
    int add = partials[blockIdx.x];
    if (add == 0) return;
    int4 v = ((int4*)S)[blockIdx.x * 256 + threadIdx.x];
    v.x += add; v.y += add; v.z += add; v.w += add;
    ((int4*)S)[blockIdx.x * 256 + threadIdx.x] = v;
}

// scatter point ids; S[c] becomes end-of-range (range c = [S[c-1], S[c]))
__global__ void scatter_points_kernel(const int* __restrict__ coors, const float* __restrict__ mask,
                                      const int* __restrict__ state, int n,
                                      int* __restrict__ S, int* __restrict__ entries) {
    int i = blockIdx.x * blockDim.x + threadIdx.x;
    if (i >= n) return;
    const int4 c = ((const int4*)coors)[i];
    int cell = ((c.x * IZ + c.y) * IY + c.z) * IX + c.w;
    float thr = __uint_as_float((unsigned)state[0]);
    int imp = (mask[i] >= thr) ? 1 : 0;
    int pos = atomicAdd(&S[cell], 1);
    entries[pos] = (i << 1) | imp;
}

// ---------- main conv (r4 structure + 2-stage software pipeline) ----------
// Block = 4x8 output tile at fixed (bb, oz). Input region = 3 planes x 9 rows x 16.
// Phase 0: region S -> LDS. Phase 1: points into 6 (plane, y-parity) bins.
// Phase 2: taps round-robin over 4 waves; weight column in regs; scan bin.
// Software pipeline: on finding a hit, ISSUE its 8 wave-uniform feat loads,
// then COMPUTE the previous pending hit (loads have had a full scan interval
// to land), then rename. Hides L2 latency under inter-hit scan work.

__global__ void __launch_bounds__(256)
conv_kernel(const float* __restrict__ feat, const float* __restrict__ Wt,
            const int* __restrict__ S, const int* __restrict__ entries,
            float* __restrict__ out) {
    __shared__ float accS[TOY * TOX][COUT];       // 8 KB
    __shared__ int   keepS[TOY * TOX];
    __shared__ int   sLds[NROW][17];              // 1836 B
    __shared__ unsigned work[6][CAPB];            // 9 KB
    __shared__ int   cnt[6];
    __shared__ int   notDone;

    int tid = threadIdx.x;
    int w = tid >> 6;
    int lane = tid & 63;

    int tile = blockIdx.x;
    int oyT = (tile % (OD1 / TOY)) * TOY;
    int rest = tile / (OD1 / TOY);
    int oz = rest % OD0;
    int bb = rest / OD0;

    // zero accumulators
    {
        float4 z = make_float4(0.f, 0.f, 0.f, 0.f);
        float4* a4 = (float4*)&accS[0][0];
        a4[tid] = z;
        a4[tid + 256] = z;
        if (tid < TOY * TOX) keepS[tid] = 0;
    }

    // ---- phase 0: region S -> LDS (27 rows x 17 values, coalesced) ----
    for (int idx = tid; idx < NROW * 17; idx += 256) {
        int row = idx / 17, j = idx % 17;
        int plane = row / 9, pyL = row % 9;
        int pz = 2 * oz - 1 + plane;
        int py = 2 * oyT - 1 + pyL;
        int v = 0;
        if (pz >= 0 && py >= 0) {                 // upper bounds never exceeded
            int cellFlat = ((bb * IZ + pz) * IY + py) * IX + (j - 1);
            if (cellFlat >= 0) v = S[cellFlat];
        }
        sLds[row][j] = v;
    }
    __syncthreads();

    // per-thread enumeration state (overflow-safe resume)
    int myCl[2]; int nMy = 0;
    for (int cl = tid; cl < NCELL_R; cl += 256) myCl[nMy++] = cl;
    int ci = 0;
    int pi = -1;    // next global entry index within current cell; -1 = from range start

    for (;;) {
        if (tid < 6) cnt[tid] = 0;
        if (tid == 0) notDone = 0;
        __syncthreads();

        // ---- phase 1: enumerate points into 6 bins ----
        while (ci < nMy) {
            int cl = myCl[ci];
            int row = cl >> 4, px = cl & 15;
            int rs = (pi < 0) ? sLds[row][px] : pi;
            int re = sLds[row][px + 1];
            int plane = row / 9, pyL = row % 9;
            int bin = plane * 2 + (pyL & 1);
            bool blocked = false;
            for (int i = rs; i < re; i++) {
                int pos = atomicAdd(&cnt[bin], 1);
                if (pos >= CAPB) { pi = i; blocked = true; break; }
                int e = entries[i];
                work[bin][pos] = ((unsigned)(e >> 1) << 9) | (unsigned)((e & 1) << 8)
                               | (unsigned)(pyL << 4) | (unsigned)px;
            }
            if (blocked) break;
            ci++; pi = -1;
        }
        if (ci < nMy) notDone = 1;   // benign same-value race
        __syncthreads();

        // ---- phase 2: tap-major compute, weights in registers, pipelined hits ----
        for (int t = w; t < NTAP; t += 4) {
            int o0 = t / 9, r9 = t % 9, o1 = r9 / 3, o2 = r9 % 3;
            int bin = o0 * 2 + (o1 & 1);
            int nb = cnt[bin];
            if (nb > CAPB) nb = CAPB;
            if (nb == 0) continue;

            const float4* wp = (const float4*)(Wt + ((size_t)t * COUT + lane) * CIN);
            float4 w0 = wp[0], w1 = wp[1], w2 = wp[2], w3 = wp[3];
            float4 w4 = wp[4], w5 = wp[5], w6 = wp[6], w7 = wp[7];

            // pending hit state (2-stage pipeline)
            int pcl = -1;
            float4 f0, f1, f2, f3, f4, f5, f6, f7;

            for (int j = 0; j < nb; j++) {
                unsigned e = work[bin][j];
                int pyL = (int)((e >> 4) & 15u);
                int px  = (int)(e & 15u);
                int yy = (pyL - o1) >> 1;              // parity guaranteed by bin
                if ((unsigned)yy >= (unsigned)TOY) continue;
                int dx = px + 1 - o2;
                if (dx & 1) continue;
                int ox = dx >> 1;
                if ((unsigned)ox >= (unsigned)TOX) continue;

                int pid = (int)(e >> 9);
                const float4* fp = (const float4*)(feat + (size_t)pid * CIN);
                // issue loads for current hit (wave-uniform row, 8x dwordx4)
                float4 n0 = fp[0], n1 = fp[1], n2 = fp[2], n3 = fp[3];
                float4 n4 = fp[4], n5 = fp[5], n6 = fp[6], n7 = fp[7];

                // compute previous pending hit (its loads have landed)
                if (pcl >= 0) {
                    float a0 = 0.f, a1 = 0.f, a2 = 0.f, a3 = 0.f;
                    a0 = fmaf(f0.x, w0.x, a0); a0 = fmaf(f0.y, w0.y, a0);
                    a0 = fmaf(f0.z, w0.z, a0); a0 = fmaf(f0.w, w0.w, a0);
                    a1 = fmaf(f1.x, w1.x, a1); a1 = fmaf(f1.y, w1.y, a1);
                    a1 = fmaf(f1.z, w1.z, a1); a1 = fmaf(f1.w, w1.w, a1);
                    a2 = fmaf(f2.x, w2.x, a2); a2 = fmaf(f2.y, w2.y, a2);
                    a2 = fmaf(f2.z, w2.z, a2); a2 = fmaf(f2.w, w2.w, a2);
                    a3 = fmaf(f3.x, w3.x, a3); a3 = fmaf(f3.y, w3.y, a3);
                    a3 = fmaf(f3.z, w3.z, a3); a3 = fmaf(f3.w, w3.w, a3);
                    a0 = fmaf(f4.x, w4.x, a0); a0 = fmaf(f4.y, w4.y, a0);
                    a0 = fmaf(f4.z, w4.z, a0); a0 = fmaf(f4.w, w4.w, a0);
                    a1 = fmaf(f5.x, w5.x, a1); a1 = fmaf(f5.y, w5.y, a1);
                    a1 = fmaf(f5.z, w5.z, a1); a1 = fmaf(f5.w, w5.w, a1);
                    a2 = fmaf(f6.x, w6.x, a2); a2 = fmaf(f6.y, w6.y, a2);
                    a2 = fmaf(f6.z, w6.z, a2); a2 = fmaf(f6.w, w6.w, a2);
                    a3 = fmaf(f7.x, w7.x, a3); a3 = fmaf(f7.y, w7.y, a3);
                    a3 = fmaf(f7.z, w7.z, a3); a3 = fmaf(f7.w, w7.w, a3);
                    atomicAdd(&accS[pcl][lane], (a0 + a1) + (a2 + a3));
                }

                // rename: current becomes pending
                f0 = n0; f1 = n1; f2 = n2; f3 = n3;
                f4 = n4; f5 = n5; f6 = n6; f7 = n7;
                pcl = yy * TOX + ox;
                if (lane == 0 && (e & 0x100u)) keepS[pcl] = 1;
            }

            // flush pending
            if (pcl >= 0) {
                float a0 = 0.f, a1 = 0.f, a2 = 0.f, a3 = 0.f;
                a0 = fmaf(f0.x, w0.x, a0); a0 = fmaf(f0.y, w0.y, a0);
                a0 = fmaf(f0.z, w0.z, a0); a0 = fmaf(f0.w, w0.w, a0);
                a1 = fmaf(f1.x, w1.x, a1); a1 = fmaf(f1.y, w1.y, a1);
                a1 = fmaf(f1.z, w1.z, a1); a1 = fmaf(f1.w, w1.w, a1);
                a2 = fmaf(f2.x, w2.x, a2); a2 = fmaf(f2.y, w2.y, a2);
                a2 = fmaf(f2.z, w2.z, a2); a2 = fmaf(f2.w, w2.w, a2);
                a3 = fmaf(f3.x, w3.x, a3); a3 = fmaf(f3.y, w3.y, a3);
                a3 = fmaf(f3.z, w3.z, a3); a3 = fmaf(f3.w, w3.w, a3);
                a0 = fmaf(f4.x, w4.x, a0); a0 = fmaf(f4.y, w4.y, a0);
                a0 = fmaf(f4.z, w4.z, a0); a0 = fmaf(f4.w, w4.w, a0);
                a1 = fmaf(f5.x, w5.x, a1); a1 = fmaf(f5.y, w5.y, a1);
                a1 = fmaf(f5.z, w5.z, a1); a1 = fmaf(f5.w, w5.w, a1);
                a2 = fmaf(f6.x, w6.x, a2); a2 = fmaf(f6.y, w6.y, a2);
                a2 = fmaf(f6.z, w6.z, a2); a2 = fmaf(f6.w, w6.w, a2);
                a3 = fmaf(f7.x, w7.x, a3); a3 = fmaf(f7.y, w7.y, a3);
                a3 = fmaf(f7.z, w7.z, a3); a3 = fmaf(f7.w, w7.w, a3);
                atomicAdd(&accS[pcl][lane], (a0 + a1) + (a2 + a3));
            }
        }
        __syncthreads();
        if (!notDone) break;
    }

    // ---- epilogue: wave w stores cells w*8 .. w*8+7, coalesced ----
#pragma unroll
    for (int k = 0; k < 8; k++) {
        int cl = w * 8 + k;
        int oy = oyT + (cl >> 3);
        int ox = cl & 7;
        size_t cellG = (((size_t)bb * OD0 + oz) * OD1 + oy) * OD2 + ox;
        out[cellG * COUT + lane] = keepS[cl] ? accS[cl][lane] : 0.f;
    }
}

// ================= legacy scatter path (ws too small) =================

__global__ void hist0_simple_kernel(const float* __restrict__ mask, int n, int* __restrict__ hist) {
    __shared__ int h[256];
    h[threadIdx.x] = 0;
    __syncthreads();
    for (int i = blockIdx.x * blockDim.x + threadIdx.x; i < n; i += gridDim.x * blockDim.x) {
        unsigned bits = __float_as_uint(mask[i]);
        atomicAdd(&h[bits >> 24], 1);
    }
    __syncthreads();
    int v = h[threadIdx.x];
    if (v) atomicAdd(&hist[threadIdx.x], v);
}

__global__ void __launch_bounds__(256)
scatter_kernel(const float* __restrict__ feat, const int* __restrict__ coors,
               const float* __restrict__ mask, const float* __restrict__ W,
               const int* __restrict__ state, float* __restrict__ out,
               int* __restrict__ keep, int n) {
    int gid = blockIdx.x * blockDim.x + threadIdx.x;
    int wave = gid >> 6;
    int lane = threadIdx.x & 63;
    if (wave >= n) return;

    const int4 c4 = ((const int4*)coors)[wave];
    int bb = c4.x, pz = c4.y, py = c4.z, px = c4.w;

    float thr = __uint_as_float((unsigned)state[0]);
    bool imp = mask[wave] >= thr;

    int oz[2], ozo[2], nz = 0;
    int oy[2], oyo[2], ny = 0;
    int ox[2], oxo[2], nx = 0;
#pragma unroll
    for (int o = 0; o < 3; o++) {
        int num = pz + 1 - o;
        if (num >= 0 && !(num & 1) && (num >> 1) < OD0) { oz[nz] = num >> 1; ozo[nz] = o; nz++; }
        num = py + 1 - o;
        if (num >= 0 && !(num & 1) && (num >> 1) < OD1) { oy[ny] = num >> 1; oyo[ny] = o; ny++; }
        num = px + 1 - o;
        if (num >= 0 && !(num & 1) && (num >> 1) < OD2) { ox[nx] = num >> 1; oxo[nx] = o; nx++; }
    }

    float f[CIN];
    const float4* fp = (const float4*)(feat + (size_t)wave * CIN);
#pragma unroll
    for (int j = 0; j < CIN / 4; j++) {
        float4 v = fp[j];
        f[4 * j + 0] = v.x; f[4 * j + 1] = v.y; f[4 * j + 2] = v.z; f[4 * j + 3] = v.w;
    }

    for (int a = 0; a < nz; a++)
        for (int b = 0; b < ny; b++)
            for (int c = 0; c < nx; c++) {
                int woff = ((ozo[a] * 3 + oyo[b]) * 3 + oxo[c]) * (CIN * COUT);
                const float* wcol = W + woff + lane;
                float acc = 0.f;
#pragma unroll
                for (int k = 0; k < CIN; k++) acc = fmaf(f[k], wcol[k * COUT], acc);
                int lin = ((bb * OD0 + oz[a]) * OD1 + oy[b]) * OD2 + ox[c];
                atomicAdd(out + (size_t)lin * COUT + lane, acc);
                if (imp && lane == 0) keep[lin] = 1;
            }
}

__global__ void finalize_kernel(float* __restrict__ out, const int* __restrict__ keep, int numOut) {
    int t = blockIdx.x * blockDim.x + threadIdx.x;
    if (t >= numOut * (COUT / 4)) return;
    int o = t >> 4;
    if (!keep[o]) ((float4*)out)[t] = make_float4(0.f, 0.f, 0.f, 0.f);
}

// ================= launcher =================

extern "C" void kernel_launch(void* const* d_in, const int* in_sizes, int n_in,
                              void* d_out, int out_size, void* d_ws, size_t ws_size,
                              hipStream_t stream) {
    const float* feat  = (const float*)d_in[0];   // (N, 32) f32
    const int*   coors = (const int*)d_in[1];     // (N, 4)  i32
    const float* mask  = (const float*)d_in[2];   // (N,)    f32
    const float* W     = (const float*)d_in[3];   // (3,3,3,32,64) f32

    int n = in_sizes[2];                 // N
    int numOut = out_size / COUT;        // 160000
    int rank = (int)(n * 0.5);           // int(N * PRUNING_RATIO)

    const int blk = 256;
    int gN = (n + blk - 1) / blk;

    char* ws = (char*)d_ws;

    // workspace layout
    size_t offHist    = 0;                                   // 4 x 256 ints = 4 KB
    size_t offState   = 4 * 256 * 4;                         // 64 B
    size_t offS       = offState + 64;                       // NCELLS ints = 5.12 MB (16B aligned)
    size_t offPart    = offS + (size_t)NCELLS * 4;           // 1250 ints (pad to 1280)
    size_t offEntries = offPart + 1280 * 4;                  // n ints
    size_t offWt      = offEntries + (size_t)n * 4;          // 27*64*32 f32
    size_t need       = offWt + (size_t)NTAP * CIN * COUT * 4;

    int* hist  = (int*)(ws + offHist);
    int* state = (int*)(ws + offState);

    if (ws_size >= need) {
        int*   S       = (int*)(ws + offS);
        int*   part    = (int*)(ws + offPart);
        int*   entries = (int*)(ws + offEntries);
        float* Wt      = (float*)(ws + offWt);

        hipMemsetAsync(ws, 0, offS + (size_t)NCELLS * 4, stream);   // hist + state + S

        // level 0 (fused with CSR count + W transpose), then levels 1..3
        hist0_fused_kernel<<<256, blk, 0, stream>>>(mask, coors, W, n, hist, S, Wt);
        select8_kernel<<<1, 256, 0, stream>>>(hist, state, 0, rank);
        for (int lvl = 1; lvl < 4; lvl++) {
            hist8_kernel<<<256, blk, 0, stream>>>(mask, n, lvl, state, hist + lvl * 256);
            select8_kernel<<<1, 256, 0, stream>>>(hist + lvl * 256, state, lvl, rank);
        }

        int nBlocksScan = NCELLS / 1024;                     // 1250
        scan_l0_kernel<<<nBlocksScan, 256, 0, stream>>>(S, part);
        scan_l1_kernel<<<1, 256, 0, stream>>>(part, nBlocksScan);
        scan_l2_kernel<<<nBlocksScan, 256, 0, stream>>>(S, part);
        scatter_points_kernel<<<gN, blk, 0, stream>>>(coors, mask, state, n, S, entries);

        int nTiles = numOut / (TOY * TOX);                   // 5000
        conv_kernel<<<nTiles, 256, 0, stream>>>(feat, Wt, S, entries, (float*)d_out);
    } else {
        // legacy scatter path (self-contained)
        int* keep = (int*)(ws + offS);
        hipMemsetAsync(d_out, 0, (size_t)out_size * sizeof(float), stream);
        hipMemsetAsync(ws, 0, offS + (size_t)numOut * 4, stream);

        hist0_simple_kernel<<<256, blk, 0, stream>>>(mask, n, hist);
        select8_kernel<<<1, 256, 0, stream>>>(hist, state, 0, rank);
        for (int lvl = 1; lvl < 4; lvl++) {
            hist8_kernel<<<256, blk, 0, stream>>>(mask, n, lvl, state, hist + lvl * 256);
            select8_kernel<<<1, 256, 0, stream>>>(hist + lvl * 256, state, lvl, rank);
        }

        long long threads = (long long)n * 64;
        int gScatter = (int)((threads + blk - 1) / blk);
        scatter_kernel<<<gScatter, blk, 0, stream>>>(feat, coors, mask, W, state,
                                                     (float*)d_out, keep, n);

        int fin = numOut * (COUT / 4);
        finalize_kernel<<<(fin + blk - 1) / blk, blk, 0, stream>>>((float*)d_out, keep, numOut);
    }
}